// Round 2
// baseline (736.984 us; speedup 1.0000x reference)
//
#include <hip/hip_runtime.h>

#define CH 128
#define HD 64

// ---------------- tiny precompute: folded weight products ----------------
// PsW = W_src@Wa1 [128,64], PdW = W_dst@Wa1 [128,64], M = Wp2@Wa1 [64,64],
// bias2[l] = ba1[l] + sum_c bp2[c]*Wa1[c][l]
__global__ void k_pre(const float* __restrict__ W_src, const float* __restrict__ W_dst,
                      const float* __restrict__ Wa1, const float* __restrict__ ba1,
                      const float* __restrict__ Wp2, const float* __restrict__ bp2,
                      float* __restrict__ PsW, float* __restrict__ PdW,
                      float* __restrict__ Mm, float* __restrict__ bias2)
{
    int idx = blockIdx.x * 256 + threadIdx.x;
    if (idx < 8192) {
        int k = idx >> 6, l = idx & 63;
        float a = 0.f;
        for (int c = 0; c < 128; ++c) a = fmaf(W_src[k*128+c], Wa1[c*64+l], a);
        PsW[idx] = a;
    } else if (idx < 16384) {
        int j = idx - 8192; int k = j >> 6, l = j & 63;
        float a = 0.f;
        for (int c = 0; c < 128; ++c) a = fmaf(W_dst[k*128+c], Wa1[c*64+l], a);
        PdW[j] = a;
    } else if (idx < 20480) {
        int j = idx - 16384; int h = j >> 6, l = j & 63;
        float a = 0.f;
        for (int c = 0; c < 128; ++c) a = fmaf(Wp2[h*128+c], Wa1[c*64+l], a);
        Mm[j] = a;
    } else if (idx < 20544) {
        int l = idx - 20480;
        float a = ba1[l];
        for (int c = 0; c < 128; ++c) a = fmaf(bp2[c], Wa1[c*64+l], a);
        bias2[l] = a;
    }
}

// ---------------- CSR build ----------------
__global__ void k_zero(int* __restrict__ p, int n) {
    int i = blockIdx.x * 256 + threadIdx.x;
    if (i < n) p[i] = 0;
}

__global__ void k_count(const int* __restrict__ ei, int E, int N, int* __restrict__ cnt) {
    int i = blockIdx.x * 256 + threadIdx.x;
    int T = E + N;
    if (i >= T) return;
    int dst = (i < E) ? ei[E + i] : (i - E);
    atomicAdd(&cnt[dst], 1);
}

__global__ void k_pos4(const float* __restrict__ pos, float4* __restrict__ pos4, int N) {
    int i = blockIdx.x * 256 + threadIdx.x;
    if (i < N) pos4[i] = make_float4(pos[3*i], pos[3*i+1], pos[3*i+2], 0.f);
}

__global__ __launch_bounds__(1024) void k_scan1(int* __restrict__ cnt, int* __restrict__ bsum, int N) {
    __shared__ int sc[1024];
    int t = threadIdx.x;
    int i = blockIdx.x * 1024 + t;
    int val = (i < N) ? cnt[i] : 0;
    sc[t] = val;
    __syncthreads();
    for (int off = 1; off < 1024; off <<= 1) {
        int tmp = (t >= off) ? sc[t - off] : 0;
        __syncthreads();
        sc[t] += tmp;
        __syncthreads();
    }
    int incl = sc[t];
    if (i < N) cnt[i] = incl - val;           // local exclusive
    if (t == 1023) bsum[blockIdx.x] = incl;   // block total
}

__global__ void k_scan2(int* __restrict__ bsum, int* __restrict__ offs, int nb, int N) {
    if (threadIdx.x == 0 && blockIdx.x == 0) {
        int run = 0;
        for (int i = 0; i < nb; ++i) { int tv = bsum[i]; bsum[i] = run; run += tv; }
        offs[N] = run;
    }
}

__global__ void k_scan3(int* __restrict__ offs, const int* __restrict__ bsum,
                        int* __restrict__ cursor, int N) {
    int i = blockIdx.x * 256 + threadIdx.x;
    if (i < N) {
        int o = offs[i] + bsum[i >> 10];
        offs[i] = o;
        cursor[i] = o;
    }
}

__global__ void k_scatter(const int* __restrict__ ei, int E, int N,
                          int* __restrict__ cursor, int* __restrict__ srcs) {
    int i = blockIdx.x * 256 + threadIdx.x;
    int T = E + N;
    if (i >= T) return;
    int s_, d_;
    if (i < E) { s_ = ei[i]; d_ = ei[E + i]; }
    else       { s_ = i - E; d_ = i - E; }
    int p = atomicAdd(&cursor[d_], 1);
    srcs[p] = s_;
}

// ---------------- node transform: h=relu(xW_in+b); v=hW_lin; ps=h PsW; pd=h PdW --------
__global__ __launch_bounds__(256) void k_node(
    const float* __restrict__ x, const float* __restrict__ W_in, const float* __restrict__ b_in,
    const float* __restrict__ W_lin, const float* __restrict__ PsW, const float* __restrict__ PdW,
    float* __restrict__ v, float* __restrict__ ps, float* __restrict__ pd, int N)
{
    __shared__ float xsT[128][20];
    __shared__ float hsT[128][20];
    int t = threadIdx.x;
    int r0 = blockIdx.x * 16;

    for (int idx = t; idx < 16 * 128; idx += 256) {
        int r = idx >> 7, k = idx & 127;
        int row = r0 + r;
        xsT[k][r] = (row < N) ? x[row * 128 + k] : 0.f;
    }
    __syncthreads();

    int c = t & 127, rg = t >> 7;      // rg 0..1, rows rg*8 .. rg*8+7
    float acc[8];
    {
        float b = b_in[c];
        #pragma unroll
        for (int j = 0; j < 8; ++j) acc[j] = b;
        for (int k = 0; k < 128; ++k) {
            float w = W_in[k * 128 + c];
            const float4 xa = *(const float4*)&xsT[k][rg * 8];
            const float4 xb = *(const float4*)&xsT[k][rg * 8 + 4];
            acc[0] = fmaf(xa.x, w, acc[0]); acc[1] = fmaf(xa.y, w, acc[1]);
            acc[2] = fmaf(xa.z, w, acc[2]); acc[3] = fmaf(xa.w, w, acc[3]);
            acc[4] = fmaf(xb.x, w, acc[4]); acc[5] = fmaf(xb.y, w, acc[5]);
            acc[6] = fmaf(xb.z, w, acc[6]); acc[7] = fmaf(xb.w, w, acc[7]);
        }
        #pragma unroll
        for (int j = 0; j < 8; ++j) hsT[c][rg * 8 + j] = fmaxf(acc[j], 0.f);
    }
    __syncthreads();
    // v = h @ W_lin (no bias)
    {
        #pragma unroll
        for (int j = 0; j < 8; ++j) acc[j] = 0.f;
        for (int k = 0; k < 128; ++k) {
            float w = W_lin[k * 128 + c];
            const float4 ha = *(const float4*)&hsT[k][rg * 8];
            const float4 hb = *(const float4*)&hsT[k][rg * 8 + 4];
            acc[0] = fmaf(ha.x, w, acc[0]); acc[1] = fmaf(ha.y, w, acc[1]);
            acc[2] = fmaf(ha.z, w, acc[2]); acc[3] = fmaf(ha.w, w, acc[3]);
            acc[4] = fmaf(hb.x, w, acc[4]); acc[5] = fmaf(hb.y, w, acc[5]);
            acc[6] = fmaf(hb.z, w, acc[6]); acc[7] = fmaf(hb.w, w, acc[7]);
        }
        #pragma unroll
        for (int j = 0; j < 8; ++j) {
            int row = r0 + rg * 8 + j;
            if (row < N) v[row * 128 + c] = acc[j];
        }
    }
    // ps = h @ PsW, pd = h @ PdW  (64 cols each)
    {
        int c2 = t & 63, g = t >> 6;   // g 0..3, rows g*4 .. g*4+3
        float as[4], ad[4];
        #pragma unroll
        for (int j = 0; j < 4; ++j) { as[j] = 0.f; ad[j] = 0.f; }
        for (int k = 0; k < 128; ++k) {
            float wsv = PsW[k * 64 + c2];
            float wdv = PdW[k * 64 + c2];
            const float4 h4 = *(const float4*)&hsT[k][g * 4];
            as[0] = fmaf(h4.x, wsv, as[0]); as[1] = fmaf(h4.y, wsv, as[1]);
            as[2] = fmaf(h4.z, wsv, as[2]); as[3] = fmaf(h4.w, wsv, as[3]);
            ad[0] = fmaf(h4.x, wdv, ad[0]); ad[1] = fmaf(h4.y, wdv, ad[1]);
            ad[2] = fmaf(h4.z, wdv, ad[2]); ad[3] = fmaf(h4.w, wdv, ad[3]);
        }
        #pragma unroll
        for (int j = 0; j < 4; ++j) {
            int row = r0 + g * 4 + j;
            if (row < N) { ps[row * 64 + c2] = as[j]; pd[row * 64 + c2] = ad[j]; }
        }
    }
}

// ---------------- fused edge aggregation with online per-channel softmax --------------
// ONE WAVE per workgroup. wave = (node, channel-half); 1 channel/lane.
// 192 weight values per lane MUST be register-resident: launch_bounds(64,1)
// lifts the VGPR cap to 512 (expect ~230 -> 2 waves/SIMD).
__global__ __launch_bounds__(64, 1) void k_agg(
    const float* __restrict__ v, const float* __restrict__ ps, const float* __restrict__ pd,
    const float4* __restrict__ pos4, const int* __restrict__ offs, const int* __restrict__ srcs,
    const float* __restrict__ Wp1, const float* __restrict__ bp1,
    const float* __restrict__ Wp2, const float* __restrict__ bp2,
    const float* __restrict__ Mm, const float* __restrict__ bias2,
    const float* __restrict__ Wa2, const float* __restrict__ ba2,
    float* __restrict__ out, int N, int totWaves)
{
    __shared__ float wl[144];
    int lane = threadIdx.x;
    int gw = blockIdx.x;
    int half = gw & 1;
    int cc = (half << 6) + lane;

    // register-resident weight columns (all indices compile-time after unroll)
    float m_col[64], wp2c[64], wa2c[64];
    #pragma unroll
    for (int h = 0; h < 64; ++h) {
        m_col[h] = Mm[h * 64 + lane];
        wp2c[h]  = Wp2[h * 128 + cc];
        wa2c[h]  = Wa2[h * 128 + cc];
    }
    float wp10 = Wp1[lane], wp11 = Wp1[64 + lane], wp12 = Wp1[128 + lane];
    float bp1l = bp1[lane], bias2l = bias2[lane];
    float ba2c = ba2[cc], bp2c = bp2[cc];

    int nodeStride = totWaves >> 1;
    for (int node = (gw >> 1); node < N; node += nodeStride) {
        int beg = offs[node], end = offs[node + 1];
        float pdl = pd[node * 64 + lane];
        float4 pi = pos4[node];
        float mM = -__builtin_inff(), sS = 0.f, aA = 0.f;

        int   srcC = srcs[beg];
        float pslC = ps[srcC * 64 + lane];
        float uvC  = v[srcC * 128 + cc];
        float4 pjC = pos4[srcC];

        for (int e = beg; e < end; ++e) {
            // prefetch next edge's gathers
            int en = (e + 1 < end) ? (e + 1) : e;
            int   srcN = srcs[en];
            float pslN = ps[srcN * 64 + lane];
            float uvN  = v[srcN * 128 + cc];
            float4 pjN = pos4[srcN];

            // pos_nn hidden (lane = hidden unit)
            float rx = pi.x - pjC.x, ry = pi.y - pjC.y, rz = pi.z - pjC.z;
            float phv = fmaxf(fmaf(rx, wp10, fmaf(ry, wp11, fmaf(rz, wp12, bp1l))), 0.f);
            wl[lane] = phv;

            // ah_pre[l] = pd - ps + bias2 + M^T·ph ; delta[c] = bp2 + Wp2^T·ph
            float ahp = (pdl - pslC) + bias2l;
            float dlt = bp2c;
            #pragma unroll
            for (int j = 0; j < 16; ++j) {
                const float4 p4 = *(const float4*)(wl + 4 * j);
                ahp = fmaf(p4.x, m_col[4 * j + 0], ahp);
                ahp = fmaf(p4.y, m_col[4 * j + 1], ahp);
                ahp = fmaf(p4.z, m_col[4 * j + 2], ahp);
                ahp = fmaf(p4.w, m_col[4 * j + 3], ahp);
                dlt = fmaf(p4.x, wp2c[4 * j + 0], dlt);
                dlt = fmaf(p4.y, wp2c[4 * j + 1], dlt);
                dlt = fmaf(p4.z, wp2c[4 * j + 2], dlt);
                dlt = fmaf(p4.w, wp2c[4 * j + 3], dlt);
            }
            float ahv = fmaxf(ahp, 0.f);
            wl[64 + lane] = ahv;

            float al = ba2c;
            #pragma unroll
            for (int j = 0; j < 16; ++j) {
                const float4 a4 = *(const float4*)(wl + 64 + 4 * j);
                al = fmaf(a4.x, wa2c[4 * j + 0], al);
                al = fmaf(a4.y, wa2c[4 * j + 1], al);
                al = fmaf(a4.z, wa2c[4 * j + 2], al);
                al = fmaf(a4.w, wa2c[4 * j + 3], al);
            }

            // online softmax update (per-channel independent)
            float u  = uvC + dlt;
            float nm = fmaxf(mM, al);
            float scl = __expf(mM - nm);
            float pv  = __expf(al - nm);
            sS = fmaf(sS, scl, pv);
            aA = fmaf(aA, scl, pv * u);
            mM = nm;

            srcC = srcN; pslC = pslN; uvC = uvN; pjC = pjN;
        }
        out[node * 128 + cc] = aA / (sS + 1e-16f);
    }
}

// ---------------- lin_out + residual (in-place on d_out) ----------------
__global__ __launch_bounds__(256) void k_out(
    const float* __restrict__ x, const float* __restrict__ W_out, const float* __restrict__ b_out,
    float* __restrict__ out, int N)
{
    __shared__ float csT[128][20];
    int t = threadIdx.x;
    int r0 = blockIdx.x * 16;

    for (int idx = t; idx < 16 * 128; idx += 256) {
        int r = idx >> 7, k = idx & 127;
        int row = r0 + r;
        csT[k][r] = (row < N) ? out[row * 128 + k] : 0.f;
    }
    __syncthreads();

    int c = t & 127, rg = t >> 7;
    float acc[8];
    float b = b_out[c];
    #pragma unroll
    for (int j = 0; j < 8; ++j) acc[j] = b;
    for (int k = 0; k < 128; ++k) {
        float w = W_out[k * 128 + c];
        const float4 ca = *(const float4*)&csT[k][rg * 8];
        const float4 cb = *(const float4*)&csT[k][rg * 8 + 4];
        acc[0] = fmaf(ca.x, w, acc[0]); acc[1] = fmaf(ca.y, w, acc[1]);
        acc[2] = fmaf(ca.z, w, acc[2]); acc[3] = fmaf(ca.w, w, acc[3]);
        acc[4] = fmaf(cb.x, w, acc[4]); acc[5] = fmaf(cb.y, w, acc[5]);
        acc[6] = fmaf(cb.z, w, acc[6]); acc[7] = fmaf(cb.w, w, acc[7]);
    }
    #pragma unroll
    for (int j = 0; j < 8; ++j) {
        int row = r0 + rg * 8 + j;
        if (row < N) out[row * 128 + c] = fmaxf(acc[j], 0.f) + x[row * 128 + c];
    }
}

extern "C" void kernel_launch(void* const* d_in, const int* in_sizes, int n_in,
                              void* d_out, int out_size, void* d_ws, size_t ws_size,
                              hipStream_t stream)
{
    const float* x     = (const float*)d_in[0];
    const float* pos   = (const float*)d_in[1];
    const int*   ei    = (const int*)d_in[2];
    const float* W_in  = (const float*)d_in[3];
    const float* b_in  = (const float*)d_in[4];
    const float* W_out = (const float*)d_in[5];
    const float* b_out = (const float*)d_in[6];
    const float* W_lin = (const float*)d_in[7];
    const float* W_src = (const float*)d_in[8];
    const float* W_dst = (const float*)d_in[9];
    const float* Wp1   = (const float*)d_in[10];
    const float* bp1   = (const float*)d_in[11];
    const float* Wp2   = (const float*)d_in[12];
    const float* bp2   = (const float*)d_in[13];
    const float* Wa1   = (const float*)d_in[14];
    const float* ba1   = (const float*)d_in[15];
    const float* Wa2   = (const float*)d_in[16];
    const float* ba2   = (const float*)d_in[17];

    int N = in_sizes[0] / 128;
    int E = in_sizes[2] / 2;
    int T = E + N;
    float* out = (float*)d_out;

    char* w = (char*)d_ws;
    auto alloc = [&](size_t bytes) -> char* {
        char* p = w;
        w += (bytes + 255) & ~(size_t)255;
        return p;
    };
    float* v_    = (float*)alloc((size_t)N * 128 * 4);
    float* ps_   = (float*)alloc((size_t)N * 64 * 4);
    float* pd_   = (float*)alloc((size_t)N * 64 * 4);
    float4* pos4 = (float4*)alloc((size_t)N * 16);
    float* PsW   = (float*)alloc(8192 * 4);
    float* PdW   = (float*)alloc(8192 * 4);
    float* Mm    = (float*)alloc(4096 * 4);
    float* bias2 = (float*)alloc(64 * 4);
    int*   offs  = (int*)alloc((size_t)(N + 1) * 4);
    int*   cursor= (int*)alloc((size_t)N * 4);
    int*   bsum  = (int*)alloc(256 * 4);
    int*   srcs  = (int*)alloc((size_t)T * 4);

    k_pre<<<dim3(81), dim3(256), 0, stream>>>(W_src, W_dst, Wa1, ba1, Wp2, bp2, PsW, PdW, Mm, bias2);
    k_zero<<<dim3((N + 1 + 255) / 256), dim3(256), 0, stream>>>(offs, N + 1);
    k_count<<<dim3((T + 255) / 256), dim3(256), 0, stream>>>(ei, E, N, offs);
    k_pos4<<<dim3((N + 255) / 256), dim3(256), 0, stream>>>(pos, pos4, N);
    int nb = (N + 1023) / 1024;
    k_scan1<<<dim3(nb), dim3(1024), 0, stream>>>(offs, bsum, N);
    k_scan2<<<dim3(1), dim3(64), 0, stream>>>(bsum, offs, nb, N);
    k_scan3<<<dim3((N + 255) / 256), dim3(256), 0, stream>>>(offs, bsum, cursor, N);
    k_scatter<<<dim3((T + 255) / 256), dim3(256), 0, stream>>>(ei, E, N, cursor, srcs);
    k_node<<<dim3((N + 15) / 16), dim3(256), 0, stream>>>(x, W_in, b_in, W_lin, PsW, PdW, v_, ps_, pd_, N);
    int totWaves = 8192;
    k_agg<<<dim3(totWaves), dim3(64), 0, stream>>>(v_, ps_, pd_, pos4, offs, srcs,
                                                   Wp1, bp1, Wp2, bp2, Mm, bias2, Wa2, ba2,
                                                   out, N, totWaves);
    k_out<<<dim3((N + 15) / 16), dim3(256), 0, stream>>>(x, W_out, b_out, out, N);
}

// Round 3
// 552.605 us; speedup vs baseline: 1.3337x; 1.3337x over previous
//
#include <hip/hip_runtime.h>

typedef _Float16 h2_t __attribute__((ext_vector_type(2)));

static __device__ __forceinline__ float fdot2f(unsigned int a, unsigned int b, float c) {
#if __has_builtin(__builtin_amdgcn_fdot2)
    return __builtin_amdgcn_fdot2(__builtin_bit_cast(h2_t, a), __builtin_bit_cast(h2_t, b), c, false);
#else
    float d;
    asm volatile("v_dot2_f32_f16 %0, %1, %2, %3" : "=v"(d) : "v"(a), "v"(b), "v"(c));
    return d;
#endif
}

static __device__ __forceinline__ unsigned int packh2(float a, float b) {
    h2_t h;
    h.x = (_Float16)a;
    h.y = (_Float16)b;
    return __builtin_bit_cast(unsigned int, h);
}

// ---------------- precompute: folded weight products, fp16-packed ----------------
// PsW = W_src@Wa1 [128,64] f32, PdW = W_dst@Wa1 [128,64] f32 (consumed by k_node)
// Mpk[t*64+l]  = pack(M[2t][l], M[2t+1][l]),  M = Wp2@Wa1 [64,64]
// Wp2pk[t*128+c] = pack(Wp2[2t][c], Wp2[2t+1][c])
// Wa2pk[t*128+c] = pack(Wa2[2t][c], Wa2[2t+1][c])
// bias2[l] = ba1[l] + sum_c bp2[c]*Wa1[c][l]
__global__ void k_pre(const float* __restrict__ W_src, const float* __restrict__ W_dst,
                      const float* __restrict__ Wa1, const float* __restrict__ ba1,
                      const float* __restrict__ Wp2, const float* __restrict__ bp2,
                      const float* __restrict__ Wa2,
                      float* __restrict__ PsW, float* __restrict__ PdW,
                      unsigned int* __restrict__ Mpk, unsigned int* __restrict__ Wp2pk,
                      unsigned int* __restrict__ Wa2pk, float* __restrict__ bias2)
{
    int idx = blockIdx.x * 256 + threadIdx.x;
    if (idx < 8192) {
        int k = idx >> 6, l = idx & 63;
        float a = 0.f;
        for (int c = 0; c < 128; ++c) a = fmaf(W_src[k*128+c], Wa1[c*64+l], a);
        PsW[idx] = a;
    } else if (idx < 16384) {
        int j = idx - 8192; int k = j >> 6, l = j & 63;
        float a = 0.f;
        for (int c = 0; c < 128; ++c) a = fmaf(W_dst[k*128+c], Wa1[c*64+l], a);
        PdW[j] = a;
    } else if (idx < 18432) {
        int j = idx - 16384; int t = j >> 6, l = j & 63;
        float m0 = 0.f, m1 = 0.f;
        for (int c = 0; c < 128; ++c) {
            m0 = fmaf(Wp2[(2*t)*128+c],   Wa1[c*64+l], m0);
            m1 = fmaf(Wp2[(2*t+1)*128+c], Wa1[c*64+l], m1);
        }
        Mpk[j] = packh2(m0, m1);
    } else if (idx < 22528) {
        int j = idx - 18432; int t = j >> 7, c = j & 127;
        Wp2pk[j] = packh2(Wp2[(2*t)*128+c], Wp2[(2*t+1)*128+c]);
    } else if (idx < 26624) {
        int j = idx - 22528; int t = j >> 7, c = j & 127;
        Wa2pk[j] = packh2(Wa2[(2*t)*128+c], Wa2[(2*t+1)*128+c]);
    } else if (idx < 26688) {
        int l = idx - 26624;
        float a = ba1[l];
        for (int c = 0; c < 128; ++c) a = fmaf(bp2[c], Wa1[c*64+l], a);
        bias2[l] = a;
    }
}

// ---------------- CSR build ----------------
__global__ void k_zero(int* __restrict__ p, int n) {
    int i = blockIdx.x * 256 + threadIdx.x;
    if (i < n) p[i] = 0;
}

__global__ void k_count(const int* __restrict__ ei, int E, int N, int* __restrict__ cnt) {
    int i = blockIdx.x * 256 + threadIdx.x;
    int T = E + N;
    if (i >= T) return;
    int dst = (i < E) ? ei[E + i] : (i - E);
    atomicAdd(&cnt[dst], 1);
}

__global__ void k_pos4(const float* __restrict__ pos, float4* __restrict__ pos4, int N) {
    int i = blockIdx.x * 256 + threadIdx.x;
    if (i < N) pos4[i] = make_float4(pos[3*i], pos[3*i+1], pos[3*i+2], 0.f);
}

__global__ __launch_bounds__(1024) void k_scan1(int* __restrict__ cnt, int* __restrict__ bsum, int N) {
    __shared__ int sc[1024];
    int t = threadIdx.x;
    int i = blockIdx.x * 1024 + t;
    int val = (i < N) ? cnt[i] : 0;
    sc[t] = val;
    __syncthreads();
    for (int off = 1; off < 1024; off <<= 1) {
        int tmp = (t >= off) ? sc[t - off] : 0;
        __syncthreads();
        sc[t] += tmp;
        __syncthreads();
    }
    int incl = sc[t];
    if (i < N) cnt[i] = incl - val;           // local exclusive
    if (t == 1023) bsum[blockIdx.x] = incl;   // block total
}

__global__ void k_scan2(int* __restrict__ bsum, int* __restrict__ offs, int nb, int N) {
    if (threadIdx.x == 0 && blockIdx.x == 0) {
        int run = 0;
        for (int i = 0; i < nb; ++i) { int tv = bsum[i]; bsum[i] = run; run += tv; }
        offs[N] = run;
    }
}

__global__ void k_scan3(int* __restrict__ offs, const int* __restrict__ bsum,
                        int* __restrict__ cursor, int N) {
    int i = blockIdx.x * 256 + threadIdx.x;
    if (i < N) {
        int o = offs[i] + bsum[i >> 10];
        offs[i] = o;
        cursor[i] = o;
    }
}

__global__ void k_scatter(const int* __restrict__ ei, int E, int N,
                          int* __restrict__ cursor, int* __restrict__ srcs) {
    int i = blockIdx.x * 256 + threadIdx.x;
    int T = E + N;
    if (i >= T) return;
    int s_, d_;
    if (i < E) { s_ = ei[i]; d_ = ei[E + i]; }
    else       { s_ = i - E; d_ = i - E; }
    int p = atomicAdd(&cursor[d_], 1);
    srcs[p] = s_;
}

// ---------------- node transform: h=relu(xW_in+b); v=hW_lin; ps=h PsW; pd=h PdW --------
__global__ __launch_bounds__(256) void k_node(
    const float* __restrict__ x, const float* __restrict__ W_in, const float* __restrict__ b_in,
    const float* __restrict__ W_lin, const float* __restrict__ PsW, const float* __restrict__ PdW,
    float* __restrict__ v, float* __restrict__ ps, float* __restrict__ pd, int N)
{
    __shared__ float xsT[128][20];
    __shared__ float hsT[128][20];
    int t = threadIdx.x;
    int r0 = blockIdx.x * 16;

    for (int idx = t; idx < 16 * 128; idx += 256) {
        int r = idx >> 7, k = idx & 127;
        int row = r0 + r;
        xsT[k][r] = (row < N) ? x[row * 128 + k] : 0.f;
    }
    __syncthreads();

    int c = t & 127, rg = t >> 7;      // rg 0..1, rows rg*8 .. rg*8+7
    float acc[8];
    {
        float b = b_in[c];
        #pragma unroll
        for (int j = 0; j < 8; ++j) acc[j] = b;
        for (int k = 0; k < 128; ++k) {
            float w = W_in[k * 128 + c];
            const float4 xa = *(const float4*)&xsT[k][rg * 8];
            const float4 xb = *(const float4*)&xsT[k][rg * 8 + 4];
            acc[0] = fmaf(xa.x, w, acc[0]); acc[1] = fmaf(xa.y, w, acc[1]);
            acc[2] = fmaf(xa.z, w, acc[2]); acc[3] = fmaf(xa.w, w, acc[3]);
            acc[4] = fmaf(xb.x, w, acc[4]); acc[5] = fmaf(xb.y, w, acc[5]);
            acc[6] = fmaf(xb.z, w, acc[6]); acc[7] = fmaf(xb.w, w, acc[7]);
        }
        #pragma unroll
        for (int j = 0; j < 8; ++j) hsT[c][rg * 8 + j] = fmaxf(acc[j], 0.f);
    }
    __syncthreads();
    // v = h @ W_lin (no bias)
    {
        #pragma unroll
        for (int j = 0; j < 8; ++j) acc[j] = 0.f;
        for (int k = 0; k < 128; ++k) {
            float w = W_lin[k * 128 + c];
            const float4 ha = *(const float4*)&hsT[k][rg * 8];
            const float4 hb = *(const float4*)&hsT[k][rg * 8 + 4];
            acc[0] = fmaf(ha.x, w, acc[0]); acc[1] = fmaf(ha.y, w, acc[1]);
            acc[2] = fmaf(ha.z, w, acc[2]); acc[3] = fmaf(ha.w, w, acc[3]);
            acc[4] = fmaf(hb.x, w, acc[4]); acc[5] = fmaf(hb.y, w, acc[5]);
            acc[6] = fmaf(hb.z, w, acc[6]); acc[7] = fmaf(hb.w, w, acc[7]);
        }
        #pragma unroll
        for (int j = 0; j < 8; ++j) {
            int row = r0 + rg * 8 + j;
            if (row < N) v[row * 128 + c] = acc[j];
        }
    }
    // ps = h @ PsW, pd = h @ PdW  (64 cols each)
    {
        int c2 = t & 63, g = t >> 6;   // g 0..3, rows g*4 .. g*4+3
        float as[4], ad[4];
        #pragma unroll
        for (int j = 0; j < 4; ++j) { as[j] = 0.f; ad[j] = 0.f; }
        for (int k = 0; k < 128; ++k) {
            float wsv = PsW[k * 64 + c2];
            float wdv = PdW[k * 64 + c2];
            const float4 h4 = *(const float4*)&hsT[k][g * 4];
            as[0] = fmaf(h4.x, wsv, as[0]); as[1] = fmaf(h4.y, wsv, as[1]);
            as[2] = fmaf(h4.z, wsv, as[2]); as[3] = fmaf(h4.w, wsv, as[3]);
            ad[0] = fmaf(h4.x, wdv, ad[0]); ad[1] = fmaf(h4.y, wdv, ad[1]);
            ad[2] = fmaf(h4.z, wdv, ad[2]); ad[3] = fmaf(h4.w, wdv, ad[3]);
        }
        #pragma unroll
        for (int j = 0; j < 4; ++j) {
            int row = r0 + g * 4 + j;
            if (row < N) { ps[row * 64 + c2] = as[j]; pd[row * 64 + c2] = ad[j]; }
        }
    }
}

// ---------------- fused edge aggregation, fp16-packed dot2 inner loops ----------------
// ONE WAVE per workgroup; wave = (node, channel-half); lane = channel (and hidden idx).
// Packed weights: 96 VGPRs instead of 192 floats; 96 v_dot2_f32_f16 per edge.
__global__ __launch_bounds__(64, 2) void k_agg(
    const float* __restrict__ v, const float* __restrict__ ps, const float* __restrict__ pd,
    const float4* __restrict__ pos4, const int* __restrict__ offs, const int* __restrict__ srcs,
    const float* __restrict__ Wp1, const float* __restrict__ bp1,
    const float* __restrict__ bias2, const float* __restrict__ bp2, const float* __restrict__ ba2,
    const unsigned int* __restrict__ Mpk, const unsigned int* __restrict__ Wp2pk,
    const unsigned int* __restrict__ Wa2pk,
    float* __restrict__ out, int N, int totWaves)
{
    __shared__ __align__(16) unsigned int wlh[64];   // halves: [0..63]=ph, [64..127]=ahv
    int lane = threadIdx.x;
    int gw = blockIdx.x;
    int half = gw & 1;
    int cc = (half << 6) + lane;

    // packed fp16 weight columns (compile-time indices after unroll)
    unsigned int mcol[32], wp2c[32], wa2c[32];
    #pragma unroll
    for (int t = 0; t < 32; ++t) {
        mcol[t] = Mpk[t * 64 + lane];
        wp2c[t] = Wp2pk[t * 128 + cc];
        wa2c[t] = Wa2pk[t * 128 + cc];
    }
    float wp10 = Wp1[lane], wp11 = Wp1[64 + lane], wp12 = Wp1[128 + lane];
    float bp1l = bp1[lane], bias2l = bias2[lane];
    float ba2c = ba2[cc], bp2c = bp2[cc];

    _Float16* wlph = (_Float16*)wlh;
    const uint4* wl4 = (const uint4*)wlh;

    int nodeStride = totWaves >> 1;
    for (int node = (gw >> 1); node < N; node += nodeStride) {
        int beg = offs[node], end = offs[node + 1];
        float pdl = pd[node * 64 + lane];
        float4 pi = pos4[node];
        float mM = -__builtin_inff(), sS = 0.f, aA = 0.f;

        int   srcC = srcs[beg];
        float pslC = ps[srcC * 64 + lane];
        float uvC  = v[srcC * 128 + cc];
        float4 pjC = pos4[srcC];

        for (int e = beg; e < end; ++e) {
            // prefetch next edge's gathers
            int en = (e + 1 < end) ? (e + 1) : e;
            int   srcN = srcs[en];
            float pslN = ps[srcN * 64 + lane];
            float uvN  = v[srcN * 128 + cc];
            float4 pjN = pos4[srcN];

            // pos_nn hidden (lane = hidden unit), packed to LDS as fp16
            float rx = pi.x - pjC.x, ry = pi.y - pjC.y, rz = pi.z - pjC.z;
            float phv = fmaxf(fmaf(rx, wp10, fmaf(ry, wp11, fmaf(rz, wp12, bp1l))), 0.f);
            wlph[lane] = (_Float16)phv;

            // ah_pre[l] = pd-ps+bias2 + M^T·ph ; delta[c] = bp2 + Wp2^T·ph
            float ahp0 = (pdl - pslC) + bias2l, ahp1 = 0.f;
            float dlt0 = bp2c, dlt1 = 0.f;
            #pragma unroll
            for (int j = 0; j < 8; ++j) {
                uint4 q = wl4[j];
                ahp0 = fdot2f(q.x, mcol[4*j+0], ahp0);
                dlt0 = fdot2f(q.x, wp2c[4*j+0], dlt0);
                ahp1 = fdot2f(q.y, mcol[4*j+1], ahp1);
                dlt1 = fdot2f(q.y, wp2c[4*j+1], dlt1);
                ahp0 = fdot2f(q.z, mcol[4*j+2], ahp0);
                dlt0 = fdot2f(q.z, wp2c[4*j+2], dlt0);
                ahp1 = fdot2f(q.w, mcol[4*j+3], ahp1);
                dlt1 = fdot2f(q.w, wp2c[4*j+3], dlt1);
            }
            float ahv = fmaxf(ahp0 + ahp1, 0.f);
            float dlt = dlt0 + dlt1;
            wlph[64 + lane] = (_Float16)ahv;

            // alpha[c] = ba2 + Wa2^T·ahv
            float al0 = ba2c, al1 = 0.f;
            #pragma unroll
            for (int j = 8; j < 16; ++j) {
                uint4 q = wl4[j];
                al0 = fdot2f(q.x, wa2c[4*(j-8)+0], al0);
                al1 = fdot2f(q.y, wa2c[4*(j-8)+1], al1);
                al0 = fdot2f(q.z, wa2c[4*(j-8)+2], al0);
                al1 = fdot2f(q.w, wa2c[4*(j-8)+3], al1);
            }
            float al = al0 + al1;

            // online softmax update (per-channel independent)
            float u  = uvC + dlt;
            float nm = fmaxf(mM, al);
            float scl = __expf(mM - nm);
            float pv  = __expf(al - nm);
            sS = fmaf(sS, scl, pv);
            aA = fmaf(aA, scl, pv * u);
            mM = nm;

            srcC = srcN; pslC = pslN; uvC = uvN; pjC = pjN;
        }
        out[node * 128 + cc] = aA / (sS + 1e-16f);
    }
}

// ---------------- lin_out + residual (in-place on d_out) ----------------
__global__ __launch_bounds__(256) void k_out(
    const float* __restrict__ x, const float* __restrict__ W_out, const float* __restrict__ b_out,
    float* __restrict__ out, int N)
{
    __shared__ float csT[128][20];
    int t = threadIdx.x;
    int r0 = blockIdx.x * 16;

    for (int idx = t; idx < 16 * 128; idx += 256) {
        int r = idx >> 7, k = idx & 127;
        int row = r0 + r;
        csT[k][r] = (row < N) ? out[row * 128 + k] : 0.f;
    }
    __syncthreads();

    int c = t & 127, rg = t >> 7;
    float acc[8];
    float b = b_out[c];
    #pragma unroll
    for (int j = 0; j < 8; ++j) acc[j] = b;
    for (int k = 0; k < 128; ++k) {
        float w = W_out[k * 128 + c];
        const float4 ca = *(const float4*)&csT[k][rg * 8];
        const float4 cb = *(const float4*)&csT[k][rg * 8 + 4];
        acc[0] = fmaf(ca.x, w, acc[0]); acc[1] = fmaf(ca.y, w, acc[1]);
        acc[2] = fmaf(ca.z, w, acc[2]); acc[3] = fmaf(ca.w, w, acc[3]);
        acc[4] = fmaf(cb.x, w, acc[4]); acc[5] = fmaf(cb.y, w, acc[5]);
        acc[6] = fmaf(cb.z, w, acc[6]); acc[7] = fmaf(cb.w, w, acc[7]);
    }
    #pragma unroll
    for (int j = 0; j < 8; ++j) {
        int row = r0 + rg * 8 + j;
        if (row < N) out[row * 128 + c] = fmaxf(acc[j], 0.f) + x[row * 128 + c];
    }
}

extern "C" void kernel_launch(void* const* d_in, const int* in_sizes, int n_in,
                              void* d_out, int out_size, void* d_ws, size_t ws_size,
                              hipStream_t stream)
{
    const float* x     = (const float*)d_in[0];
    const float* pos   = (const float*)d_in[1];
    const int*   ei    = (const int*)d_in[2];
    const float* W_in  = (const float*)d_in[3];
    const float* b_in  = (const float*)d_in[4];
    const float* W_out = (const float*)d_in[5];
    const float* b_out = (const float*)d_in[6];
    const float* W_lin = (const float*)d_in[7];
    const float* W_src = (const float*)d_in[8];
    const float* W_dst = (const float*)d_in[9];
    const float* Wp1   = (const float*)d_in[10];
    const float* bp1   = (const float*)d_in[11];
    const float* Wp2   = (const float*)d_in[12];
    const float* bp2   = (const float*)d_in[13];
    const float* Wa1   = (const float*)d_in[14];
    const float* ba1   = (const float*)d_in[15];
    const float* Wa2   = (const float*)d_in[16];
    const float* ba2   = (const float*)d_in[17];

    int N = in_sizes[0] / 128;
    int E = in_sizes[2] / 2;
    int T = E + N;
    float* out = (float*)d_out;

    char* w = (char*)d_ws;
    auto alloc = [&](size_t bytes) -> char* {
        char* p = w;
        w += (bytes + 255) & ~(size_t)255;
        return p;
    };
    float* v_    = (float*)alloc((size_t)N * 128 * 4);
    float* ps_   = (float*)alloc((size_t)N * 64 * 4);
    float* pd_   = (float*)alloc((size_t)N * 64 * 4);
    float4* pos4 = (float4*)alloc((size_t)N * 16);
    float* PsW   = (float*)alloc(8192 * 4);
    float* PdW   = (float*)alloc(8192 * 4);
    unsigned int* Mpk   = (unsigned int*)alloc(2048 * 4);
    unsigned int* Wp2pk = (unsigned int*)alloc(4096 * 4);
    unsigned int* Wa2pk = (unsigned int*)alloc(4096 * 4);
    float* bias2 = (float*)alloc(64 * 4);
    int*   offs  = (int*)alloc((size_t)(N + 1) * 4);
    int*   cursor= (int*)alloc((size_t)N * 4);
    int*   bsum  = (int*)alloc(256 * 4);
    int*   srcs  = (int*)alloc((size_t)T * 4);

    k_pre<<<dim3(105), dim3(256), 0, stream>>>(W_src, W_dst, Wa1, ba1, Wp2, bp2, Wa2,
                                               PsW, PdW, Mpk, Wp2pk, Wa2pk, bias2);
    k_zero<<<dim3((N + 1 + 255) / 256), dim3(256), 0, stream>>>(offs, N + 1);
    k_count<<<dim3((T + 255) / 256), dim3(256), 0, stream>>>(ei, E, N, offs);
    k_pos4<<<dim3((N + 255) / 256), dim3(256), 0, stream>>>(pos, pos4, N);
    int nb = (N + 1023) / 1024;
    k_scan1<<<dim3(nb), dim3(1024), 0, stream>>>(offs, bsum, N);
    k_scan2<<<dim3(1), dim3(64), 0, stream>>>(bsum, offs, nb, N);
    k_scan3<<<dim3((N + 255) / 256), dim3(256), 0, stream>>>(offs, bsum, cursor, N);
    k_scatter<<<dim3((T + 255) / 256), dim3(256), 0, stream>>>(ei, E, N, cursor, srcs);
    k_node<<<dim3((N + 15) / 16), dim3(256), 0, stream>>>(x, W_in, b_in, W_lin, PsW, PdW, v_, ps_, pd_, N);
    int totWaves = 8192;
    k_agg<<<dim3(totWaves), dim3(64), 0, stream>>>(v_, ps_, pd_, pos4, offs, srcs,
                                                   Wp1, bp1, bias2, bp2, ba2,
                                                   Mpk, Wp2pk, Wa2pk,
                                                   out, N, totWaves);
    k_out<<<dim3((N + 15) / 16), dim3(256), 0, stream>>>(x, W_out, b_out, out, N);
}